// Round 1
// baseline (524.598 us; speedup 1.0000x reference)
//
#include <hip/hip_runtime.h>
#include <math.h>

// Problem constants (from reference): B=32, Q=4096, G=32, C=128
#define NB   32
#define BQ   4096
#define GMAX 32
#define NC   128
#define BS   512            // threads per block
#define CPT  (BQ / BS)      // 8 columns per thread, strided: j = k*BS + tid
#define NWAVE (BS / 64)     // 8 waves

// One block per batch. Replicates the reference JV shortest-augmenting-path
// Hungarian exactly (f64 state, f32 cost with reference op order, first-index
// argmin tie-break).
__launch_bounds__(BS, 1)
__global__ void matcher_kernel(const float* __restrict__ sem,    // [B,Q,C]
                               const float* __restrict__ objp,   // [B,Q]
                               const float* __restrict__ cent,   // [B,Q,G]
                               const float* __restrict__ giou,   // [B,Q,G]
                               const int*   __restrict__ labels, // [B,G]
                               const int*   __restrict__ nact,   // [B]
                               float* __restrict__ out)          // [2*B*Q]
{
    const int b   = blockIdx.x;
    const int tid = threadIdx.x;
    const int m   = BQ;   // number of columns (proposals); rows = gt (ng <= 32)

    __shared__ double v_lds[BQ + 1];
    __shared__ double u_lds[GMAX];
    __shared__ unsigned short way[BQ];   // predecessor column (<= m fits u16)
    __shared__ short p_lds[BQ + 1];      // matched row per column, -1 = none
    __shared__ unsigned char used[BQ + 1];
    __shared__ int usedList[GMAX + 4];
    __shared__ int lab_sh[GMAX];
    __shared__ double redv[NWAVE];
    __shared__ int    redj[NWAVE];
    __shared__ double s_delta;
    __shared__ int s_j0, s_i0, s_done, s_nused;

    // ---- per-batch init ----
    for (int k = tid; k < BQ + 1; k += BS) { v_lds[k] = 0.0; p_lds[k] = -1; }
    if (tid < GMAX) { u_lds[tid] = 0.0; lab_sh[tid] = labels[b * GMAX + tid]; }
    const int ng = nact[b];
    __syncthreads();

    // i0-independent part of the cost: 0.5f * objectness (exact in f32)
    float hobj[CPT];
#pragma unroll
    for (int k = 0; k < CPT; k++) {
        int j = k * BS + tid;
        hobj[k] = __fmul_rn(0.5f, objp[b * BQ + j]);
    }

    const double INF = (double)INFINITY;
    double minv[CPT];   // owner-exclusive, lives in VGPRs

    for (int i = 0; i < ng; i++) {
        // ---- per-row reset ----
#pragma unroll
        for (int k = 0; k < CPT; k++) {
            int j = k * BS + tid;
            used[j] = 0;
            minv[k] = INF;
        }
        if (tid == 0) {
            used[m] = 0;
            p_lds[m] = (short)i;
            s_j0 = m;
            s_nused = 0;
        }
        __syncthreads();

        while (true) {
            // step A: mark current column used (thread 0)
            if (tid == 0) {
                int j0 = s_j0;
                used[j0] = 1;
                usedList[s_nused++] = j0;
                s_i0 = (int)p_lds[j0];
            }
            __syncthreads();

            const int i0  = s_i0;
            const int j0c = s_j0;
            const double ui0 = u_lds[i0];
            const int lab = lab_sh[i0];
            const size_t sbase = ((size_t)b * BQ) * NC + (size_t)lab;
            const int cbase = (b * BQ) * GMAX + i0;

            // relax + per-thread argmin (ascending j => strict '<' keeps first)
            double bestv = INF;
            int    bestj = m;
#pragma unroll
            for (int k = 0; k < CPT; k++) {
                int j = k * BS + tid;
                if (!used[j]) {
                    float pcls = sem[sbase + (size_t)j * NC];
                    float ce   = cent[cbase + j * GMAX];
                    float gi   = giou[cbase + j * GMAX];
                    // ((1*(-p) - 0.5*obj) + 1*center) - 2*giou, f32 per-op rounding
                    float cost = __fsub_rn(__fadd_rn(__fsub_rn(-pcls, hobj[k]), ce),
                                           __fmul_rn(2.0f, gi));
                    double cur = ((double)cost - ui0) - v_lds[j];
                    if (cur < minv[k]) { minv[k] = cur; way[j] = (unsigned short)j0c; }
                    double mv = minv[k];
                    if (mv < bestv) { bestv = mv; bestj = j; }
                }
            }

            // wave-level lexicographic (val, idx) min
#pragma unroll
            for (int off = 32; off >= 1; off >>= 1) {
                double ov = __shfl_down(bestv, off, 64);
                int    oj = __shfl_down(bestj, off, 64);
                if (ov < bestv || (ov == bestv && oj < bestj)) { bestv = ov; bestj = oj; }
            }
            const int wave = tid >> 6;
            if ((tid & 63) == 0) { redv[wave] = bestv; redj[wave] = bestj; }
            __syncthreads();

            // wave 0: final reduce + parallel dual-variable update
            if (tid < 64) {
                double fv = (tid < NWAVE) ? redv[tid] : INF;
                int    fj = (tid < NWAVE) ? redj[tid] : m;
#pragma unroll
                for (int off = 4; off >= 1; off >>= 1) {
                    double ov = __shfl_down(fv, off, 64);
                    int    oj = __shfl_down(fj, off, 64);
                    if (ov < fv || (ov == fv && oj < fj)) { fv = ov; fj = oj; }
                }
                double delta = __shfl(fv, 0, 64);
                int    j1    = __shfl(fj, 0, 64);
                int nu = s_nused;   // includes current j0, not j1 (matches numpy)
                if (tid < nu) {
                    int jc = usedList[tid];
                    int rc = (int)p_lds[jc];   // rows distinct across used cols
                    u_lds[rc] += delta;
                    v_lds[jc] -= delta;
                }
                if (tid == 0) {
                    s_delta = delta;
                    s_j0 = j1;
                    s_done = (p_lds[j1] == -1) ? 1 : 0;
                }
            }
            __syncthreads();

            // minv -= delta for unused columns (matches numpy step order)
            const double delta = s_delta;
#pragma unroll
            for (int k = 0; k < CPT; k++) {
                int j = k * BS + tid;
                if (!used[j]) minv[k] -= delta;
            }
            if (s_done) break;
            __syncthreads();   // protect used[]/minv reads vs next step A write
        }

        // ---- augment along the path (serial, short) ----
        __syncthreads();
        if (tid == 0) {
            int j0 = s_j0;
            while (j0 != m) {
                int j1 = (int)way[j0];
                p_lds[j0] = p_lds[j1];
                j0 = j1;
            }
        }
        __syncthreads();
    }

    // ---- write outputs: [per_prop (B*Q), mask (B*Q)] as float ----
#pragma unroll
    for (int k = 0; k < CPT; k++) {
        int j = k * BS + tid;
        short pj = p_lds[j];
        out[(size_t)b * BQ + j] = (pj >= 0) ? (float)pj : 0.0f;
        out[(size_t)NB * BQ + (size_t)b * BQ + j] = (pj >= 0) ? 1.0f : 0.0f;
    }
}

extern "C" void kernel_launch(void* const* d_in, const int* in_sizes, int n_in,
                              void* d_out, int out_size, void* d_ws, size_t ws_size,
                              hipStream_t stream) {
    const float* sem    = (const float*)d_in[0];  // [B,Q,C]
    const float* objp   = (const float*)d_in[1];  // [B,Q]
    const float* cent   = (const float*)d_in[2];  // [B,Q,G]
    const float* giou   = (const float*)d_in[3];  // [B,Q,G]
    const int*   labels = (const int*)d_in[4];    // [B,G]
    const int*   nact   = (const int*)d_in[5];    // [B]
    float* out = (float*)d_out;                   // [2*B*Q]

    matcher_kernel<<<NB, BS, 0, stream>>>(sem, objp, cent, giou, labels, nact, out);
}

// Round 2
// 266.942 us; speedup vs baseline: 1.9652x; 1.9652x over previous
//
#include <hip/hip_runtime.h>
#include <math.h>

// Problem constants (from reference): B=32, Q=4096, G=32, C=128
#define NB   32
#define BQ   4096
#define GMAX 32
#define NC   128
#define BS   512            // solver threads per block
#define CPT  (BQ / BS)      // 8 columns per thread, strided: j = k*BS + tid
#define NWAVE (BS / 64)     // 8 waves

#define TQ   64             // q-tile per build block
#define BBS  256            // build block size

// ---------------- Kernel 1: cost build ----------------
// cost[b][i][q] = -sem[b,q,lab_i] - 0.5*obj[b,q] + cent[b,q,i] - 2*giou[b,q,i]
// exact f32 per-op rounding in reference order. Only rows i < ng are written.
__launch_bounds__(BBS)
__global__ void build_cost_kernel(const float* __restrict__ sem,
                                  const float* __restrict__ objp,
                                  const float* __restrict__ cent,
                                  const float* __restrict__ giou,
                                  const int*   __restrict__ labels,
                                  const int*   __restrict__ nact,
                                  float* __restrict__ cost)   // [B][G][Q]
{
    const int b  = blockIdx.y;
    const int q0 = blockIdx.x * TQ;
    const int tid = threadIdx.x;

    __shared__ float sem_sh[TQ][NC + 1];   // 64 x 129 x 4B = 33 KB, pad kills conflicts
    __shared__ int lab_sh[GMAX];

    if (tid < GMAX) lab_sh[tid] = labels[b * GMAX + tid];
    const int ng = nact[b];

    // coalesced float4 staging of sem[b, q0:q0+64, 0:128] (8192 floats)
    const float4* semb = (const float4*)(sem + ((size_t)b * BQ + q0) * NC);
    for (int r = tid; r < TQ * NC / 4; r += BBS) {
        float4 vv = semb[r];
        int e = r * 4;
        int qq = e >> 7;          // /NC
        int cc = e & (NC - 1);
        sem_sh[qq][cc]     = vv.x;
        sem_sh[qq][cc + 1] = vv.y;
        sem_sh[qq][cc + 2] = vv.z;
        sem_sh[qq][cc + 3] = vv.w;
    }
    __syncthreads();

    const int qi = tid & (TQ - 1);    // 0..63 (lane id within wave)
    const int ig = tid >> 6;          // 0..3  (i-subrange)
    const int q  = q0 + qi;
    const float ho = __fmul_rn(0.5f, objp[b * BQ + q]);
    const float* centq = cent + ((size_t)b * BQ + q) * GMAX;
    const float* giouq = giou + ((size_t)b * BQ + q) * GMAX;

    for (int i = ig; i < ng; i += 4) {
        float pcls = sem_sh[qi][lab_sh[i]];
        float ce   = centq[i];
        float gi   = giouq[i];
        float c = __fsub_rn(__fadd_rn(__fsub_rn(-pcls, ho), ce),
                            __fmul_rn(2.0f, gi));
        cost[((size_t)b * GMAX + i) * BQ + q] = c;   // 256B coalesced per wave
    }
}

// ---------------- Kernel 2: JV Hungarian solver ----------------
// One block per batch. Exact replica of the reference JV shortest augmenting
// path (f64 state, first-index argmin tie-break).
__launch_bounds__(BS, 1)
__global__ void matcher_kernel(const float* __restrict__ cost,   // [B][G][Q]
                               const int*   __restrict__ nact,   // [B]
                               float* __restrict__ out)          // [2*B*Q]
{
    const int b   = blockIdx.x;
    const int tid = threadIdx.x;
    const int m   = BQ;

    __shared__ double v_lds[BQ + 1];
    __shared__ double u_lds[GMAX];
    __shared__ unsigned short way[BQ];
    __shared__ short p_lds[BQ + 1];
    __shared__ unsigned char used[BQ + 1];
    __shared__ int usedList[GMAX + 4];
    __shared__ double redv[NWAVE];
    __shared__ int    redj[NWAVE];
    __shared__ double s_delta;
    __shared__ int s_j0, s_i0, s_done, s_nused;

    for (int k = tid; k < BQ + 1; k += BS) { v_lds[k] = 0.0; p_lds[k] = -1; }
    if (tid < GMAX) u_lds[tid] = 0.0;
    const int ng = nact[b];
    __syncthreads();

    const double INF = (double)INFINITY;
    double minv[CPT];   // owner-exclusive, strided ownership j = k*BS + tid

    for (int i = 0; i < ng; i++) {
#pragma unroll
        for (int k = 0; k < CPT; k++) {
            int j = k * BS + tid;
            used[j] = 0;
            minv[k] = INF;
        }
        if (tid == 0) {
            used[m] = 0;
            p_lds[m] = (short)i;
            s_j0 = m;
            s_nused = 0;
        }
        __syncthreads();

        while (true) {
            if (tid == 0) {
                int j0 = s_j0;
                used[j0] = 1;
                usedList[s_nused++] = j0;
                s_i0 = (int)p_lds[j0];
            }
            __syncthreads();

            const int i0  = s_i0;
            const int j0c = s_j0;
            const double ui0 = u_lds[i0];
            const float* crow = cost + ((size_t)b * GMAX + i0) * BQ;

            double bestv = INF;
            int    bestj = m;
#pragma unroll
            for (int k = 0; k < CPT; k++) {
                int j = k * BS + tid;
                if (!used[j]) {
                    double cur = ((double)crow[j] - ui0) - v_lds[j];
                    if (cur < minv[k]) { minv[k] = cur; way[j] = (unsigned short)j0c; }
                    double mv = minv[k];
                    if (mv < bestv) { bestv = mv; bestj = j; }
                }
            }

            // wave-level lexicographic (val, idx) min
#pragma unroll
            for (int off = 32; off >= 1; off >>= 1) {
                double ov = __shfl_down(bestv, off, 64);
                int    oj = __shfl_down(bestj, off, 64);
                if (ov < bestv || (ov == bestv && oj < bestj)) { bestv = ov; bestj = oj; }
            }
            const int wave = tid >> 6;
            if ((tid & 63) == 0) { redv[wave] = bestv; redj[wave] = bestj; }
            __syncthreads();

            if (tid < 64) {
                double fv = (tid < NWAVE) ? redv[tid] : INF;
                int    fj = (tid < NWAVE) ? redj[tid] : m;
#pragma unroll
                for (int off = 4; off >= 1; off >>= 1) {
                    double ov = __shfl_down(fv, off, 64);
                    int    oj = __shfl_down(fj, off, 64);
                    if (ov < fv || (ov == fv && oj < fj)) { fv = ov; fj = oj; }
                }
                double delta = __shfl(fv, 0, 64);
                int    j1    = __shfl(fj, 0, 64);
                int nu = s_nused;
                if (tid < nu) {
                    int jc = usedList[tid];
                    int rc = (int)p_lds[jc];
                    u_lds[rc] += delta;
                    v_lds[jc] -= delta;
                }
                if (tid == 0) {
                    s_delta = delta;
                    s_j0 = j1;
                    s_done = (p_lds[j1] == -1) ? 1 : 0;
                }
            }
            __syncthreads();

            const double delta = s_delta;
#pragma unroll
            for (int k = 0; k < CPT; k++) {
                int j = k * BS + tid;
                if (!used[j]) minv[k] -= delta;
            }
            if (s_done) break;
            __syncthreads();
        }

        __syncthreads();
        if (tid == 0) {
            int j0 = s_j0;
            while (j0 != m) {
                int j1 = (int)way[j0];
                p_lds[j0] = p_lds[j1];
                j0 = j1;
            }
        }
        __syncthreads();
    }

#pragma unroll
    for (int k = 0; k < CPT; k++) {
        int j = k * BS + tid;
        short pj = p_lds[j];
        out[(size_t)b * BQ + j] = (pj >= 0) ? (float)pj : 0.0f;
        out[(size_t)NB * BQ + (size_t)b * BQ + j] = (pj >= 0) ? 1.0f : 0.0f;
    }
}

extern "C" void kernel_launch(void* const* d_in, const int* in_sizes, int n_in,
                              void* d_out, int out_size, void* d_ws, size_t ws_size,
                              hipStream_t stream) {
    const float* sem    = (const float*)d_in[0];  // [B,Q,C]
    const float* objp   = (const float*)d_in[1];  // [B,Q]
    const float* cent   = (const float*)d_in[2];  // [B,Q,G]
    const float* giou   = (const float*)d_in[3];  // [B,Q,G]
    const int*   labels = (const int*)d_in[4];    // [B,G]
    const int*   nact   = (const int*)d_in[5];    // [B]
    float* out  = (float*)d_out;                  // [2*B*Q]
    float* cost = (float*)d_ws;                   // [B][G][Q] = 16 MB

    dim3 bgrid(BQ / TQ, NB);
    build_cost_kernel<<<bgrid, BBS, 0, stream>>>(sem, objp, cent, giou,
                                                 labels, nact, cost);
    matcher_kernel<<<NB, BS, 0, stream>>>(cost, nact, out);
}

// Round 3
// 259.068 us; speedup vs baseline: 2.0249x; 1.0304x over previous
//
#include <hip/hip_runtime.h>
#include <math.h>

// Problem constants (from reference): B=32, Q=4096, G=32, C=128
#define NB   32
#define BQ   4096
#define GMAX 32
#define NC   128
#define BS   512            // solver threads per block
#define CPT  (BQ / BS)      // 8 columns per thread, strided: j = k*BS + tid
#define NWAVE (BS / 64)     // 8 waves

#define TQ   64             // q-tile per build block
#define BBS  256            // build block size

// ---------------- Kernel 1: cost build ----------------
// cost[b][i][q] = -sem[b,q,lab_i] - 0.5*obj[b,q] + cent[b,q,i] - 2*giou[b,q,i]
// exact f32 per-op rounding in reference order. Only rows i < ng are written.
// All global reads/writes fully coalesced via LDS staging.
__launch_bounds__(BBS)
__global__ void build_cost_kernel(const float* __restrict__ sem,
                                  const float* __restrict__ objp,
                                  const float* __restrict__ cent,
                                  const float* __restrict__ giou,
                                  const int*   __restrict__ labels,
                                  const int*   __restrict__ nact,
                                  float* __restrict__ cost)   // [B][G][Q]
{
    const int b  = blockIdx.y;
    const int q0 = blockIdx.x * TQ;
    const int tid = threadIdx.x;

    __shared__ float sem_sh[TQ][NC + 1];     // 33 KB
    __shared__ float cent_sh[TQ][GMAX + 1];  // 8.25 KB
    __shared__ float giou_sh[TQ][GMAX + 1];  // 8.25 KB
    __shared__ int lab_sh[GMAX];

    if (tid < GMAX) lab_sh[tid] = labels[b * GMAX + tid];
    const int ng = nact[b];

    // coalesced float4 staging of sem[b, q0:q0+64, 0:128]
    const float4* semb = (const float4*)(sem + ((size_t)b * BQ + q0) * NC);
    for (int r = tid; r < TQ * NC / 4; r += BBS) {
        float4 vv = semb[r];
        int e = r * 4;
        int qq = e >> 7;          // /NC
        int cc = e & (NC - 1);
        sem_sh[qq][cc]     = vv.x;
        sem_sh[qq][cc + 1] = vv.y;
        sem_sh[qq][cc + 2] = vv.z;
        sem_sh[qq][cc + 3] = vv.w;
    }
    // coalesced float4 staging of cent/giou[b, q0:q0+64, 0:32] (contiguous 8KB)
    const float4* centb = (const float4*)(cent + ((size_t)b * BQ + q0) * GMAX);
    const float4* gioub = (const float4*)(giou + ((size_t)b * BQ + q0) * GMAX);
    for (int r = tid; r < TQ * GMAX / 4; r += BBS) {
        float4 cv = centb[r];
        float4 gv = gioub[r];
        int e = r * 4;
        int qq = e >> 5;          // /GMAX
        int ii = e & (GMAX - 1);
        cent_sh[qq][ii]     = cv.x;
        cent_sh[qq][ii + 1] = cv.y;
        cent_sh[qq][ii + 2] = cv.z;
        cent_sh[qq][ii + 3] = cv.w;
        giou_sh[qq][ii]     = gv.x;
        giou_sh[qq][ii + 1] = gv.y;
        giou_sh[qq][ii + 2] = gv.z;
        giou_sh[qq][ii + 3] = gv.w;
    }
    __syncthreads();

    const int qi = tid & (TQ - 1);    // 0..63 (lane id within wave)
    const int ig = tid >> 6;          // 0..3  (i-subrange)
    const int q  = q0 + qi;
    const float ho = __fmul_rn(0.5f, objp[b * BQ + q]);

    for (int i = ig; i < ng; i += 4) {
        float pcls = sem_sh[qi][lab_sh[i]];
        float ce   = cent_sh[qi][i];
        float gi   = giou_sh[qi][i];
        float c = __fsub_rn(__fadd_rn(__fsub_rn(-pcls, ho), ce),
                            __fmul_rn(2.0f, gi));
        cost[((size_t)b * GMAX + i) * BQ + q] = c;   // 256B coalesced per wave
    }
}

// ---------------- Kernel 2: JV Hungarian solver ----------------
// One block per batch. Exact replica of the reference JV shortest augmenting
// path (f64 state, first-index argmin tie-break). Owner-exclusive state
// (v, minv, used, enterD) lives in registers; dual updates applied in closed
// form at Dijkstra end (same f64 values as the reference's per-step updates).
__launch_bounds__(BS, 1)
__global__ void matcher_kernel(const float* __restrict__ cost,   // [B][G][Q]
                               const int*   __restrict__ nact,   // [B]
                               float* __restrict__ out)          // [2*B*Q]
{
    const int b   = blockIdx.x;
    const int tid = threadIdx.x;
    const int m   = BQ;

    __shared__ short p_lds[BQ + 1];      // matched row per column, -1 = none
    __shared__ unsigned short way[BQ];   // predecessor column at min time
    __shared__ double u_lds[GMAX];
    __shared__ double redv[NWAVE];
    __shared__ int    redj[NWAVE];
    __shared__ int    step_i0[GMAX + 2];   // row entering at step t
    __shared__ double step_D[GMAX + 2];    // cumulative delta BEFORE step t

    for (int k = tid; k < BQ + 1; k += BS) p_lds[k] = -1;
    if (tid < GMAX) u_lds[tid] = 0.0;
    const int ng = nact[b];
    __syncthreads();

    const double INF = (double)INFINITY;
    double v_reg[CPT];     // column potential, owner-exclusive
    double minv[CPT];
    double enterD[CPT];    // cumulative delta when column entered used set
#pragma unroll
    for (int k = 0; k < CPT; k++) v_reg[k] = 0.0;

    for (int i = 0; i < ng; i++) {
#pragma unroll
        for (int k = 0; k < CPT; k++) minv[k] = INF;
        unsigned used_mask = 0;
        int j0 = m;           // all threads track j0 consistently
        double D = 0.0;       // cumulative delta (identical on all threads)
        int nsteps = 0;

        while (true) {
            const int i0 = (j0 == m) ? i : (int)p_lds[j0];   // LDS broadcast
            const double ui0 = u_lds[i0];
            const float* crow = cost + ((size_t)b * GMAX + i0) * BQ;

            // relax + per-thread lexicographic argmin over owned columns
            double bestv = INF;
            int    bestj = m;
#pragma unroll
            for (int k = 0; k < CPT; k++) {
                if (!((used_mask >> k) & 1u)) {
                    int j = k * BS + tid;
                    double cur = ((double)crow[j] - ui0) - v_reg[k];
                    if (cur < minv[k]) { minv[k] = cur; way[j] = (unsigned short)j0; }
                    double mv = minv[k];
                    if (mv < bestv) { bestv = mv; bestj = k * BS + tid; }
                }
            }

            // wave-level lexicographic (val, idx) min
#pragma unroll
            for (int off = 32; off >= 1; off >>= 1) {
                double ov = __shfl_down(bestv, off, 64);
                int    oj = __shfl_down(bestj, off, 64);
                if (ov < bestv || (ov == bestv && oj < bestj)) { bestv = ov; bestj = oj; }
            }
            const int wave = tid >> 6;
            if ((tid & 63) == 0) { redv[wave] = bestv; redj[wave] = bestj; }
            __syncthreads();                               // B1

            // every thread reduces the 8 partials identically (broadcast reads)
            double delta = redv[0]; int j1 = redj[0];
#pragma unroll
            for (int w = 1; w < NWAVE; w++) {
                double ov = redv[w]; int oj = redj[w];
                if (ov < delta || (ov == delta && oj < j1)) { delta = ov; j1 = oj; }
            }

            if (tid == 0) { step_i0[nsteps] = i0; step_D[nsteps] = D; }
            D += delta;
            nsteps++;

#pragma unroll
            for (int k = 0; k < CPT; k++)
                if (!((used_mask >> k) & 1u)) minv[k] -= delta;

            const bool done = (p_lds[j1] == -1);
            j0 = j1;
            if (done) break;

            // owner of j1 marks it used (enters used set at next step)
            if ((j1 & (BS - 1)) == tid) {
                int k1 = j1 / BS;
                used_mask |= (1u << k1);
                enterD[k1] = D;
            }
            __syncthreads();                               // B2 (WAR on redv/redj)
        }

        // closed-form dual updates (identical values to per-step reference)
#pragma unroll
        for (int k = 0; k < CPT; k++)
            if ((used_mask >> k) & 1u) v_reg[k] -= (D - enterD[k]);

        __syncthreads();   // way/step arrays visible; redv WAR for next row
        if (tid < nsteps) u_lds[step_i0[tid]] += D - step_D[tid];  // distinct rows
        if (tid == 0) {
            // augment along the path
            int jc = j0;
            while (jc != m) {
                int jp = (int)way[jc];
                p_lds[jc] = (jp == m) ? (short)i : p_lds[jp];
                jc = jp;
            }
        }
        __syncthreads();
    }

    // ---- write outputs: [per_prop (B*Q), mask (B*Q)] as float ----
#pragma unroll
    for (int k = 0; k < CPT; k++) {
        int j = k * BS + tid;
        short pj = p_lds[j];
        out[(size_t)b * BQ + j] = (pj >= 0) ? (float)pj : 0.0f;
        out[(size_t)NB * BQ + (size_t)b * BQ + j] = (pj >= 0) ? 1.0f : 0.0f;
    }
}

extern "C" void kernel_launch(void* const* d_in, const int* in_sizes, int n_in,
                              void* d_out, int out_size, void* d_ws, size_t ws_size,
                              hipStream_t stream) {
    const float* sem    = (const float*)d_in[0];  // [B,Q,C]
    const float* objp   = (const float*)d_in[1];  // [B,Q]
    const float* cent   = (const float*)d_in[2];  // [B,Q,G]
    const float* giou   = (const float*)d_in[3];  // [B,Q,G]
    const int*   labels = (const int*)d_in[4];    // [B,G]
    const int*   nact   = (const int*)d_in[5];    // [B]
    float* out  = (float*)d_out;                  // [2*B*Q]
    float* cost = (float*)d_ws;                   // [B][G][Q] = 16 MB

    dim3 bgrid(BQ / TQ, NB);
    build_cost_kernel<<<bgrid, BBS, 0, stream>>>(sem, objp, cent, giou,
                                                 labels, nact, cost);
    matcher_kernel<<<NB, BS, 0, stream>>>(cost, nact, out);
}

// Round 4
// 208.066 us; speedup vs baseline: 2.5213x; 1.2451x over previous
//
#include <hip/hip_runtime.h>
#include <math.h>

// Problem constants (from reference): B=32, Q=4096, G=32, C=128
#define NB   32
#define BQ   4096
#define GMAX 32
#define NC   128
#define BS   512            // solver threads per block
#define CPT  (BQ / BS)      // 8 contiguous columns per thread: j = tid*8 + k
#define NWAVE (BS / 64)     // 8 waves

#define TQ   32             // q-tile per build block
#define BBS  256            // build block size

// ---------------- Kernel 1: cost build ----------------
// cost[b][i][q] = -sem[b,q,lab_i] - 0.5*obj[b,q] + cent[b,q,i] - 2*giou[b,q,i]
// exact f32 per-op rounding in reference order. Only rows i < ng are written.
__launch_bounds__(BBS)
__global__ void build_cost_kernel(const float* __restrict__ sem,
                                  const float* __restrict__ objp,
                                  const float* __restrict__ cent,
                                  const float* __restrict__ giou,
                                  const int*   __restrict__ labels,
                                  const int*   __restrict__ nact,
                                  float* __restrict__ cost)   // [B][G][Q]
{
    const int b  = blockIdx.y;
    const int q0 = blockIdx.x * TQ;
    const int tid = threadIdx.x;

    __shared__ float sem_sh[TQ][NC + 1];     // 16.5 KB (pad: read banks qi+lab)
    __shared__ float cent_sh[TQ][GMAX + 1];  // 4.2 KB
    __shared__ float giou_sh[TQ][GMAX + 1];  // 4.2 KB
    __shared__ int lab_sh[GMAX];

    if (tid < GMAX) lab_sh[tid] = labels[b * GMAX + tid];
    const int ng = nact[b];

    // coalesced float4 staging of sem[b, q0:q0+32, 0:128] (4 iters)
    const float4* semb = (const float4*)(sem + ((size_t)b * BQ + q0) * NC);
#pragma unroll
    for (int r = tid; r < TQ * NC / 4; r += BBS) {
        float4 vv = semb[r];
        int e = r * 4;
        int qq = e >> 7;
        int cc = e & (NC - 1);
        sem_sh[qq][cc]     = vv.x;
        sem_sh[qq][cc + 1] = vv.y;
        sem_sh[qq][cc + 2] = vv.z;
        sem_sh[qq][cc + 3] = vv.w;
    }
    // coalesced float4 staging of cent/giou[b, q0:q0+32, 0:32] (1 iter each)
    {
        const float4* centb = (const float4*)(cent + ((size_t)b * BQ + q0) * GMAX);
        const float4* gioub = (const float4*)(giou + ((size_t)b * BQ + q0) * GMAX);
        int r = tid;   // TQ*GMAX/4 == 256 == BBS
        float4 cv = centb[r];
        float4 gv = gioub[r];
        int e = r * 4;
        int qq = e >> 5;
        int ii = e & (GMAX - 1);
        cent_sh[qq][ii]     = cv.x;
        cent_sh[qq][ii + 1] = cv.y;
        cent_sh[qq][ii + 2] = cv.z;
        cent_sh[qq][ii + 3] = cv.w;
        giou_sh[qq][ii]     = gv.x;
        giou_sh[qq][ii + 1] = gv.y;
        giou_sh[qq][ii + 2] = gv.z;
        giou_sh[qq][ii + 3] = gv.w;
    }
    __syncthreads();

    const int qi = tid & (TQ - 1);    // 0..31
    const int ig = tid >> 5;          // 0..7
    const int q  = q0 + qi;
    const float ho = __fmul_rn(0.5f, objp[b * BQ + q]);

    for (int i = ig; i < ng; i += 8) {
        float pcls = sem_sh[qi][lab_sh[i]];
        float ce   = cent_sh[qi][i];
        float gi   = giou_sh[qi][i];
        float c = __fsub_rn(__fadd_rn(__fsub_rn(-pcls, ho), ce),
                            __fmul_rn(2.0f, gi));
        cost[((size_t)b * GMAX + i) * BQ + q] = c;
    }
}

// ---------------- Kernel 2: JV Hungarian solver ----------------
// One block per batch. Exact replica of the reference JV shortest augmenting
// path (f64 state, first-index argmin tie-break). Owner-exclusive state in
// registers; closed-form dual updates at Dijkstra end (bit-identical values).
// Single __syncthreads per Dijkstra step via ping-pong partial buffers.
__launch_bounds__(BS, 1)
__global__ void matcher_kernel(const float* __restrict__ cost,   // [B][G][Q]
                               const int*   __restrict__ nact,   // [B]
                               float* __restrict__ out)          // [2*B*Q]
{
    const int b   = blockIdx.x;
    const int tid = threadIdx.x;
    const int m   = BQ;

    __shared__ short p_lds[BQ + 1];      // matched row per column, -1 = none
    __shared__ unsigned short way[BQ];   // predecessor column at min time
    __shared__ double u_lds[GMAX];
    __shared__ double redv[2][NWAVE];
    __shared__ int    redj[2][NWAVE];
    __shared__ int    step_i0[GMAX + 2];
    __shared__ double step_D[GMAX + 2];

    for (int k = tid; k < BQ + 1; k += BS) p_lds[k] = -1;
    if (tid < GMAX) u_lds[tid] = 0.0;
    const int ng = nact[b];
    __syncthreads();

    const double INF = (double)INFINITY;
    const int jbase = tid * CPT;         // contiguous ownership
    double v_reg[CPT];
    double minv[CPT];
    double enterD[CPT];
#pragma unroll
    for (int k = 0; k < CPT; k++) v_reg[k] = 0.0;

    for (int i = 0; i < ng; i++) {
#pragma unroll
        for (int k = 0; k < CPT; k++) minv[k] = INF;
        unsigned used_mask = 0;
        int i0 = i, j0 = m, ns = 0, buf = 0, jfin;
        double D = 0.0;

        while (true) {
            // issue row loads first (2 x dwordx4, fully coalesced, L2-hot)
            const float4* crow4 =
                (const float4*)(cost + ((size_t)b * GMAX + i0) * BQ) + tid * 2;
            float4 c0 = crow4[0];
            float4 c1 = crow4[1];
            if (tid == 0) { step_i0[ns] = i0; step_D[ns] = D; }
            const double ui0 = u_lds[i0];
            float cf[CPT] = {c0.x, c0.y, c0.z, c0.w, c1.x, c1.y, c1.z, c1.w};

            // relax + per-thread lexicographic argmin (ascending k == asc. j)
            double bestv = INF;
            int    bestj = m;
#pragma unroll
            for (int k = 0; k < CPT; k++) {
                if (!((used_mask >> k) & 1u)) {
                    double cur = ((double)cf[k] - ui0) - v_reg[k];
                    if (cur < minv[k]) { minv[k] = cur; way[jbase + k] = (unsigned short)j0; }
                    if (minv[k] < bestv) { bestv = minv[k]; bestj = jbase + k; }
                }
            }

            // wave-level lexicographic (val, idx) min
#pragma unroll
            for (int off = 32; off >= 1; off >>= 1) {
                double ov = __shfl_down(bestv, off, 64);
                int    oj = __shfl_down(bestj, off, 64);
                if (ov < bestv || (ov == bestv && oj < bestj)) { bestv = ov; bestj = oj; }
            }
            const int wave = tid >> 6;
            if ((tid & 63) == 0) { redv[buf][wave] = bestv; redj[buf][wave] = bestj; }
            __syncthreads();                                   // the ONLY barrier

            // redundant final reduce on every thread (LDS broadcast reads)
            double delta = redv[buf][0]; int j1 = redj[buf][0];
#pragma unroll
            for (int w = 1; w < NWAVE; w++) {
                double ov = redv[buf][w]; int oj = redj[buf][w];
                if (ov < delta || (ov == delta && oj < j1)) { delta = ov; j1 = oj; }
            }
            D += delta;
            ns++;

            const int pi = p_lds[j1];   // broadcast: done-check AND next i0

#pragma unroll
            for (int k = 0; k < CPT; k++)
                if (!((used_mask >> k) & 1u)) minv[k] -= delta;

            if (pi < 0) { jfin = j1; break; }

            // owner of j1 marks it used (enters used set next step)
            unsigned kk = (unsigned)(j1 - jbase);
            if (kk < CPT) { used_mask |= (1u << kk); enterD[kk] = D; }

            i0 = pi; j0 = j1; buf ^= 1;
        }

        // closed-form dual updates (identical f64 values to per-step updates)
#pragma unroll
        for (int k = 0; k < CPT; k++)
            if ((used_mask >> k) & 1u) v_reg[k] -= (D - enterD[k]);

        __syncthreads();   // way/step logs visible to all
        if (tid < ns) u_lds[step_i0[tid]] += D - step_D[tid];  // distinct rows
        if (tid == 0) {
            int jc = jfin;
            while (jc != m) {
                int jp = (int)way[jc];
                p_lds[jc] = (jp == m) ? (short)i : p_lds[jp];
                jc = jp;
            }
        }
        __syncthreads();
    }

    // ---- write outputs: [per_prop (B*Q), mask (B*Q)] as float ----
#pragma unroll
    for (int k = 0; k < CPT; k++) {
        int j = jbase + k;
        short pj = p_lds[j];
        out[(size_t)b * BQ + j] = (pj >= 0) ? (float)pj : 0.0f;
        out[(size_t)NB * BQ + (size_t)b * BQ + j] = (pj >= 0) ? 1.0f : 0.0f;
    }
}

extern "C" void kernel_launch(void* const* d_in, const int* in_sizes, int n_in,
                              void* d_out, int out_size, void* d_ws, size_t ws_size,
                              hipStream_t stream) {
    const float* sem    = (const float*)d_in[0];  // [B,Q,C]
    const float* objp   = (const float*)d_in[1];  // [B,Q]
    const float* cent   = (const float*)d_in[2];  // [B,Q,G]
    const float* giou   = (const float*)d_in[3];  // [B,Q,G]
    const int*   labels = (const int*)d_in[4];    // [B,G]
    const int*   nact   = (const int*)d_in[5];    // [B]
    float* out  = (float*)d_out;                  // [2*B*Q]
    float* cost = (float*)d_ws;                   // [B][G][Q] = 16 MB

    dim3 bgrid(BQ / TQ, NB);
    build_cost_kernel<<<bgrid, BBS, 0, stream>>>(sem, objp, cent, giou,
                                                 labels, nact, cost);
    matcher_kernel<<<NB, BS, 0, stream>>>(cost, nact, out);
}

// Round 5
// 203.531 us; speedup vs baseline: 2.5775x; 1.0223x over previous
//
#include <hip/hip_runtime.h>
#include <math.h>

// Problem constants (from reference): B=32, Q=4096, G=32, C=128
#define NB   32
#define BQ   4096
#define GMAX 32
#define NC   128
#define BS   512            // solver threads per block
#define CPT  (BQ / BS)      // 8 contiguous columns per thread: j = tid*8 + k
#define NWAVE (BS / 64)     // 8 waves

#define TQ   32             // q-tile per build block
#define BBS  256            // build block size

// ---------------- Kernel 1: cost build ----------------
// cost[b][i][q] = -sem[b,q,lab_i] - 0.5*obj[b,q] + cent[b,q,i] - 2*giou[b,q,i]
// exact f32 per-op rounding in reference order. Only rows i < ng are written.
__launch_bounds__(BBS)
__global__ void build_cost_kernel(const float* __restrict__ sem,
                                  const float* __restrict__ objp,
                                  const float* __restrict__ cent,
                                  const float* __restrict__ giou,
                                  const int*   __restrict__ labels,
                                  const int*   __restrict__ nact,
                                  float* __restrict__ cost)   // [B][G][Q]
{
    const int b  = blockIdx.y;
    const int q0 = blockIdx.x * TQ;
    const int tid = threadIdx.x;

    __shared__ float sem_sh[TQ][NC + 1];
    __shared__ float cent_sh[TQ][GMAX + 1];
    __shared__ float giou_sh[TQ][GMAX + 1];
    __shared__ int lab_sh[GMAX];

    if (tid < GMAX) lab_sh[tid] = labels[b * GMAX + tid];
    const int ng = nact[b];

    const float4* semb = (const float4*)(sem + ((size_t)b * BQ + q0) * NC);
#pragma unroll
    for (int r = tid; r < TQ * NC / 4; r += BBS) {
        float4 vv = semb[r];
        int e = r * 4;
        int qq = e >> 7;
        int cc = e & (NC - 1);
        sem_sh[qq][cc]     = vv.x;
        sem_sh[qq][cc + 1] = vv.y;
        sem_sh[qq][cc + 2] = vv.z;
        sem_sh[qq][cc + 3] = vv.w;
    }
    {
        const float4* centb = (const float4*)(cent + ((size_t)b * BQ + q0) * GMAX);
        const float4* gioub = (const float4*)(giou + ((size_t)b * BQ + q0) * GMAX);
        int r = tid;   // TQ*GMAX/4 == 256 == BBS
        float4 cv = centb[r];
        float4 gv = gioub[r];
        int e = r * 4;
        int qq = e >> 5;
        int ii = e & (GMAX - 1);
        cent_sh[qq][ii]     = cv.x;
        cent_sh[qq][ii + 1] = cv.y;
        cent_sh[qq][ii + 2] = cv.z;
        cent_sh[qq][ii + 3] = cv.w;
        giou_sh[qq][ii]     = gv.x;
        giou_sh[qq][ii + 1] = gv.y;
        giou_sh[qq][ii + 2] = gv.z;
        giou_sh[qq][ii + 3] = gv.w;
    }
    __syncthreads();

    const int qi = tid & (TQ - 1);
    const int ig = tid >> 5;
    const int q  = q0 + qi;
    const float ho = __fmul_rn(0.5f, objp[b * BQ + q]);

    for (int i = ig; i < ng; i += 8) {
        float pcls = sem_sh[qi][lab_sh[i]];
        float ce   = cent_sh[qi][i];
        float gi   = giou_sh[qi][i];
        float c = __fsub_rn(__fadd_rn(__fsub_rn(-pcls, ho), ce),
                            __fmul_rn(2.0f, gi));
        cost[((size_t)b * GMAX + i) * BQ + q] = c;
    }
}

// ---------------- Kernel 2: JV Hungarian solver ----------------
// One block per batch. Exact replica of the reference JV shortest augmenting
// path (f64 state, first-index argmin tie-break). Owner-exclusive state
// (v, minv, way, p) in registers; reduction payload carries p[j] packed with
// j so no dependent LDS read; next row prefetched as soon as i0 is known.
// Closed-form dual updates at phase end reproduce the reference's values.
__launch_bounds__(BS, 1)
__global__ void matcher_kernel(const float* __restrict__ cost,   // [B][G][Q]
                               const int*   __restrict__ nact,   // [B]
                               float* __restrict__ out)          // [2*B*Q]
{
    const int b   = blockIdx.x;
    const int tid = threadIdx.x;
    const int m   = BQ;

    __shared__ __align__(16) short p_lds[BQ + 8];       // matched row per col
    __shared__ __align__(16) unsigned short way_lds[BQ];
    __shared__ double u_lds[GMAX];
    __shared__ double   redv[2][NWAVE];
    __shared__ unsigned redpk[2][NWAVE];
    __shared__ int    step_i0[GMAX + 2];
    __shared__ double step_D[GMAX + 2];

    for (int k = tid; k < BQ + 8; k += BS) p_lds[k] = -1;
    if (tid < GMAX) u_lds[tid] = 0.0;
    const int ng = nact[b];
    __syncthreads();

    const double INF = (double)INFINITY;
    const int jbase = tid * CPT;
    const float4* cb4 = (const float4*)(cost + (size_t)b * GMAX * BQ);

    double v_reg[CPT], minv[CPT], enterD[CPT];
    int way_reg[CPT], p_reg[CPT];
#pragma unroll
    for (int k = 0; k < CPT; k++) { v_reg[k] = 0.0; way_reg[k] = m; enterD[k] = 0.0; }

    for (int i = 0; i < ng; i++) {
        // refresh p_reg (one ds_read_b128; p constant during the phase)
        int4 pv = ((const int4*)p_lds)[tid];
        p_reg[0] = (int)(short)(pv.x & 0xFFFF); p_reg[1] = pv.x >> 16;
        p_reg[2] = (int)(short)(pv.y & 0xFFFF); p_reg[3] = pv.y >> 16;
        p_reg[4] = (int)(short)(pv.z & 0xFFFF); p_reg[5] = pv.z >> 16;
        p_reg[6] = (int)(short)(pv.w & 0xFFFF); p_reg[7] = pv.w >> 16;

        // initial row load (row i) + its u
        const float4* r4 = cb4 + (size_t)i * (BQ / 4) + tid * 2;
        float4 c0 = r4[0];
        float4 c1 = r4[1];
        double ui0 = u_lds[i];

#pragma unroll
        for (int k = 0; k < CPT; k++) minv[k] = INF;
        unsigned used_mask = 0;
        int i0 = i, j0 = m, ns = 0, buf = 0, jfin;
        double D = 0.0;

        while (true) {
            float cf[CPT] = {c0.x, c0.y, c0.z, c0.w, c1.x, c1.y, c1.z, c1.w};

            // relax + per-thread lexicographic argmin (ascending k == asc. j)
            double bestv = INF;
            unsigned bestpk = ((unsigned)m << 8);
#pragma unroll
            for (int k = 0; k < CPT; k++) {
                bool un = !((used_mask >> k) & 1u);
                double cur = ((double)cf[k] - ui0) - v_reg[k];
                bool better = un && (cur < minv[k]);
                if (better) { minv[k] = cur; way_reg[k] = j0; }
                double mv = un ? minv[k] : INF;
                if (mv < bestv) {
                    bestv = mv;
                    bestpk = (((unsigned)(jbase + k)) << 8) | (unsigned)(p_reg[k] + 1);
                }
            }

            // wave-level lexicographic (val, packed-j) min
#pragma unroll
            for (int off = 32; off >= 1; off >>= 1) {
                double   ov  = __shfl_down(bestv, off, 64);
                unsigned opk = __shfl_down(bestpk, off, 64);
                if (ov < bestv || (ov == bestv && opk < bestpk)) { bestv = ov; bestpk = opk; }
            }
            const int wave = tid >> 6;
            if ((tid & 63) == 0) { redv[buf][wave] = bestv; redpk[buf][wave] = bestpk; }
            __syncthreads();                               // the ONLY barrier

            // redundant final reduce on every thread (LDS broadcast reads)
            double delta = redv[buf][0]; unsigned pk = redpk[buf][0];
#pragma unroll
            for (int w = 1; w < NWAVE; w++) {
                double ov = redv[buf][w]; unsigned opk = redpk[buf][w];
                if (ov < delta || (ov == delta && opk < pk)) { delta = ov; pk = opk; }
            }
            const int j1 = (int)(pk >> 8);
            const int pi = (int)(pk & 0xFFu) - 1;

            if (tid == 0) { step_i0[ns] = i0; step_D[ns] = D; }
            D += delta;
            ns++;

            if (pi < 0) { jfin = j1; break; }

            // prefetch next row + its u under the update shadow
            const float4* n4 = cb4 + (size_t)pi * (BQ / 4) + tid * 2;
            c0 = n4[0];
            c1 = n4[1];
            ui0 = u_lds[pi];

#pragma unroll
            for (int k = 0; k < CPT; k++)
                if (!((used_mask >> k) & 1u)) minv[k] -= delta;

            unsigned kk = (unsigned)(j1 - jbase);
            if (kk < CPT) { used_mask |= (1u << kk); enterD[kk] = D; }

            i0 = pi; j0 = j1; buf ^= 1;
        }

        // closed-form dual updates (identical f64 values to per-step updates)
#pragma unroll
        for (int k = 0; k < CPT; k++)
            if ((used_mask >> k) & 1u) v_reg[k] -= (D - enterD[k]);

        // dump way_reg as one packed 16B LDS write (2-way conflict == free)
        int4 wv;
        wv.x = (way_reg[0] & 0xFFFF) | (way_reg[1] << 16);
        wv.y = (way_reg[2] & 0xFFFF) | (way_reg[3] << 16);
        wv.z = (way_reg[4] & 0xFFFF) | (way_reg[5] << 16);
        wv.w = (way_reg[6] & 0xFFFF) | (way_reg[7] << 16);
        ((int4*)way_lds)[tid] = wv;

        __syncthreads();   // way/step logs visible to all
        if (tid < ns) u_lds[step_i0[tid]] += D - step_D[tid];  // distinct rows
        if (tid == 0) {
            int jc = jfin;
            while (jc != m) {
                int jp = (int)way_lds[jc];
                p_lds[jc] = (jp == m) ? (short)i : p_lds[jp];
                jc = jp;
            }
        }
        __syncthreads();
    }

    // ---- write outputs: [per_prop (B*Q), mask (B*Q)] as float ----
#pragma unroll
    for (int k = 0; k < CPT; k++) {
        int j = jbase + k;
        short pj = p_lds[j];
        out[(size_t)b * BQ + j] = (pj >= 0) ? (float)pj : 0.0f;
        out[(size_t)NB * BQ + (size_t)b * BQ + j] = (pj >= 0) ? 1.0f : 0.0f;
    }
}

extern "C" void kernel_launch(void* const* d_in, const int* in_sizes, int n_in,
                              void* d_out, int out_size, void* d_ws, size_t ws_size,
                              hipStream_t stream) {
    const float* sem    = (const float*)d_in[0];  // [B,Q,C]
    const float* objp   = (const float*)d_in[1];  // [B,Q]
    const float* cent   = (const float*)d_in[2];  // [B,Q,G]
    const float* giou   = (const float*)d_in[3];  // [B,Q,G]
    const int*   labels = (const int*)d_in[4];    // [B,G]
    const int*   nact   = (const int*)d_in[5];    // [B]
    float* out  = (float*)d_out;                  // [2*B*Q]
    float* cost = (float*)d_ws;                   // [B][G][Q] = 16 MB

    dim3 bgrid(BQ / TQ, NB);
    build_cost_kernel<<<bgrid, BBS, 0, stream>>>(sem, objp, cent, giou,
                                                 labels, nact, cost);
    matcher_kernel<<<NB, BS, 0, stream>>>(cost, nact, out);
}

// Round 6
// 142.194 us; speedup vs baseline: 3.6893x; 1.4314x over previous
//
#include <hip/hip_runtime.h>
#include <math.h>

// Problem constants (from reference): B=32, Q=4096, G=32, C=128
#define NB   32
#define BQ   4096
#define GMAX 32
#define NC   128
#define BS   512            // solver threads per block
#define CPT  (BQ / BS)      // 8 contiguous columns per thread: j = tid*8 + k
#define NWAVE (BS / 64)     // 8 waves

#define TQ   32             // q-tile per build block
#define BBS  256            // build block size

// ---------------- Kernel 1: cost build ----------------
// cost[b][i][q] = -sem[b,q,lab_i] - 0.5*obj[b,q] + cent[b,q,i] - 2*giou[b,q,i]
// exact f32 per-op rounding in reference order. Only rows i < ng are written.
__launch_bounds__(BBS)
__global__ void build_cost_kernel(const float* __restrict__ sem,
                                  const float* __restrict__ objp,
                                  const float* __restrict__ cent,
                                  const float* __restrict__ giou,
                                  const int*   __restrict__ labels,
                                  const int*   __restrict__ nact,
                                  float* __restrict__ cost)   // [B][G][Q]
{
    const int b  = blockIdx.y;
    const int q0 = blockIdx.x * TQ;
    const int tid = threadIdx.x;

    __shared__ float sem_sh[TQ][NC + 1];
    __shared__ float cent_sh[TQ][GMAX + 1];
    __shared__ float giou_sh[TQ][GMAX + 1];
    __shared__ int lab_sh[GMAX];

    if (tid < GMAX) lab_sh[tid] = labels[b * GMAX + tid];
    const int ng = nact[b];

    const float4* semb = (const float4*)(sem + ((size_t)b * BQ + q0) * NC);
#pragma unroll
    for (int r = tid; r < TQ * NC / 4; r += BBS) {
        float4 vv = semb[r];
        int e = r * 4;
        int qq = e >> 7;
        int cc = e & (NC - 1);
        sem_sh[qq][cc]     = vv.x;
        sem_sh[qq][cc + 1] = vv.y;
        sem_sh[qq][cc + 2] = vv.z;
        sem_sh[qq][cc + 3] = vv.w;
    }
    {
        const float4* centb = (const float4*)(cent + ((size_t)b * BQ + q0) * GMAX);
        const float4* gioub = (const float4*)(giou + ((size_t)b * BQ + q0) * GMAX);
        int r = tid;   // TQ*GMAX/4 == 256 == BBS
        float4 cv = centb[r];
        float4 gv = gioub[r];
        int e = r * 4;
        int qq = e >> 5;
        int ii = e & (GMAX - 1);
        cent_sh[qq][ii]     = cv.x;
        cent_sh[qq][ii + 1] = cv.y;
        cent_sh[qq][ii + 2] = cv.z;
        cent_sh[qq][ii + 3] = cv.w;
        giou_sh[qq][ii]     = gv.x;
        giou_sh[qq][ii + 1] = gv.y;
        giou_sh[qq][ii + 2] = gv.z;
        giou_sh[qq][ii + 3] = gv.w;
    }
    __syncthreads();

    const int qi = tid & (TQ - 1);
    const int ig = tid >> 5;
    const int q  = q0 + qi;
    const float ho = __fmul_rn(0.5f, objp[b * BQ + q]);

    for (int i = ig; i < ng; i += 8) {
        float pcls = sem_sh[qi][lab_sh[i]];
        float ce   = cent_sh[qi][i];
        float gi   = giou_sh[qi][i];
        float c = __fsub_rn(__fadd_rn(__fsub_rn(-pcls, ho), ce),
                            __fmul_rn(2.0f, gi));
        cost[((size_t)b * GMAX + i) * BQ + q] = c;
    }
}

// ---------------- Kernel 2: JV Hungarian solver with greedy warm start ----
// One block per batch. Dual-feasible warm start: u[i] = min_j cost[i][j],
// v = 0; greedy-assign each row to its (first-index) argmin column if free.
// Rows that collide run the exact f64 Dijkstra augmentation (first-index
// tie-break). Complementary slackness holds throughout => final matching is
// the optimal assignment; with continuous random costs the optimum is unique,
// so the output equals the reference's.
__launch_bounds__(BS, 1)
__global__ void matcher_kernel(const float* __restrict__ cost,   // [B][G][Q]
                               const int*   __restrict__ nact,   // [B]
                               float* __restrict__ out)          // [2*B*Q]
{
    const int b    = blockIdx.x;
    const int tid  = threadIdx.x;
    const int m    = BQ;
    const int wave = tid >> 6;
    const int lane = tid & 63;

    __shared__ __align__(16) short p_lds[BQ + 8];       // matched row per col
    __shared__ __align__(16) unsigned short way_lds[BQ];
    __shared__ double u_lds[GMAX];
    __shared__ double   redv[2][NWAVE];
    __shared__ unsigned redpk[2][NWAVE];
    __shared__ int    step_i0[GMAX + 2];
    __shared__ double step_D[GMAX + 2];
    __shared__ float  rmin_v[GMAX];
    __shared__ int    rmin_j[GMAX];
    __shared__ int    unmatched[GMAX];
    __shared__ int    s_nunm;

    for (int k = tid; k < BQ + 8; k += BS) p_lds[k] = -1;
    const int ng = nact[b];
    const float* cb = cost + (size_t)b * GMAX * BQ;
    __syncthreads();

    // ---- Pass 1: per-row (min, first-argmin), wave-parallel, no barriers ----
    for (int r = wave; r < ng; r += NWAVE) {
        const float4* row4 = (const float4*)(cb + (size_t)r * BQ);
        float bv = INFINITY; int bj = 0;
#pragma unroll
        for (int it = 0; it < 16; it++) {
            float4 vv = row4[lane + 64 * it];
            int j = (lane + 64 * it) * 4;       // ascending within lane
            if (vv.x < bv) { bv = vv.x; bj = j; }
            if (vv.y < bv) { bv = vv.y; bj = j + 1; }
            if (vv.z < bv) { bv = vv.z; bj = j + 2; }
            if (vv.w < bv) { bv = vv.w; bj = j + 3; }
        }
#pragma unroll
        for (int off = 32; off >= 1; off >>= 1) {
            float ov = __shfl_down(bv, off, 64);
            int   oj = __shfl_down(bj, off, 64);
            if (ov < bv || (ov == bv && oj < bj)) { bv = ov; bj = oj; }
        }
        if (lane == 0) { rmin_v[r] = bv; rmin_j[r] = bj; }
    }
    __syncthreads();

    // ---- duals + greedy assignment (thread 0, <=32 iters) ----
    if (tid < ng) u_lds[tid] = (double)rmin_v[tid];
    if (tid == 0) {
        int nu = 0;
        for (int i = 0; i < ng; i++) {
            int j = rmin_j[i];
            if (p_lds[j] < 0) p_lds[j] = (short)i;
            else unmatched[nu++] = i;           // ascending row order
        }
        s_nunm = nu;
    }
    __syncthreads();
    const int nunm = s_nunm;

    const double INF = (double)INFINITY;
    const int jbase = tid * CPT;
    const float4* cb4 = (const float4*)cb;

    double v_reg[CPT], minv[CPT], enterD[CPT];
    int way_reg[CPT], p_reg[CPT];
#pragma unroll
    for (int k = 0; k < CPT; k++) { v_reg[k] = 0.0; way_reg[k] = m; enterD[k] = 0.0; }

    for (int t = 0; t < nunm; t++) {
        const int ri = unmatched[t];

        // refresh p_reg (one ds_read_b128; p constant during the phase)
        int4 pv = ((const int4*)p_lds)[tid];
        p_reg[0] = (int)(short)(pv.x & 0xFFFF); p_reg[1] = pv.x >> 16;
        p_reg[2] = (int)(short)(pv.y & 0xFFFF); p_reg[3] = pv.y >> 16;
        p_reg[4] = (int)(short)(pv.z & 0xFFFF); p_reg[5] = pv.z >> 16;
        p_reg[6] = (int)(short)(pv.w & 0xFFFF); p_reg[7] = pv.w >> 16;

        // initial row load (row ri) + its u
        const float4* r4 = cb4 + (size_t)ri * (BQ / 4) + tid * 2;
        float4 c0 = r4[0];
        float4 c1 = r4[1];
        double ui0 = u_lds[ri];

#pragma unroll
        for (int k = 0; k < CPT; k++) minv[k] = INF;
        unsigned used_mask = 0;
        int i0 = ri, j0 = m, ns = 0, buf = 0, jfin;
        double D = 0.0;

        while (true) {
            float cf[CPT] = {c0.x, c0.y, c0.z, c0.w, c1.x, c1.y, c1.z, c1.w};

            // relax + per-thread lexicographic argmin (ascending k == asc. j)
            double bestv = INF;
            unsigned bestpk = ((unsigned)m << 8);
#pragma unroll
            for (int k = 0; k < CPT; k++) {
                bool un = !((used_mask >> k) & 1u);
                double cur = ((double)cf[k] - ui0) - v_reg[k];
                bool better = un && (cur < minv[k]);
                if (better) { minv[k] = cur; way_reg[k] = j0; }
                double mv = un ? minv[k] : INF;
                if (mv < bestv) {
                    bestv = mv;
                    bestpk = (((unsigned)(jbase + k)) << 8) | (unsigned)(p_reg[k] + 1);
                }
            }

            // wave-level lexicographic (val, packed-j) min
#pragma unroll
            for (int off = 32; off >= 1; off >>= 1) {
                double   ov  = __shfl_down(bestv, off, 64);
                unsigned opk = __shfl_down(bestpk, off, 64);
                if (ov < bestv || (ov == bestv && opk < bestpk)) { bestv = ov; bestpk = opk; }
            }
            if (lane == 0) { redv[buf][wave] = bestv; redpk[buf][wave] = bestpk; }
            __syncthreads();                               // the ONLY barrier

            // redundant final reduce on every thread (LDS broadcast reads)
            double delta = redv[buf][0]; unsigned pk = redpk[buf][0];
#pragma unroll
            for (int w = 1; w < NWAVE; w++) {
                double ov = redv[buf][w]; unsigned opk = redpk[buf][w];
                if (ov < delta || (ov == delta && opk < pk)) { delta = ov; pk = opk; }
            }
            const int j1 = (int)(pk >> 8);
            const int pi = (int)(pk & 0xFFu) - 1;

            if (tid == 0) { step_i0[ns] = i0; step_D[ns] = D; }
            D += delta;
            ns++;

            if (pi < 0) { jfin = j1; break; }

            // prefetch next row + its u under the update shadow
            const float4* n4 = cb4 + (size_t)pi * (BQ / 4) + tid * 2;
            c0 = n4[0];
            c1 = n4[1];
            ui0 = u_lds[pi];

#pragma unroll
            for (int k = 0; k < CPT; k++)
                if (!((used_mask >> k) & 1u)) minv[k] -= delta;

            unsigned kk = (unsigned)(j1 - jbase);
            if (kk < CPT) { used_mask |= (1u << kk); enterD[kk] = D; }

            i0 = pi; j0 = j1; buf ^= 1;
        }

        // closed-form dual updates (same f64 values as per-step updates)
#pragma unroll
        for (int k = 0; k < CPT; k++)
            if ((used_mask >> k) & 1u) { v_reg[k] -= (D - enterD[k]); }
#pragma unroll
        for (int k = 0; k < CPT; k++) used_mask = 0;  // (reset for clarity)

        // dump way_reg as one packed 16B LDS write
        int4 wv;
        wv.x = (way_reg[0] & 0xFFFF) | (way_reg[1] << 16);
        wv.y = (way_reg[2] & 0xFFFF) | (way_reg[3] << 16);
        wv.z = (way_reg[4] & 0xFFFF) | (way_reg[5] << 16);
        wv.w = (way_reg[6] & 0xFFFF) | (way_reg[7] << 16);
        ((int4*)way_lds)[tid] = wv;

        __syncthreads();   // way/step logs visible to all
        if (tid < ns) u_lds[step_i0[tid]] += D - step_D[tid];  // distinct rows
        if (tid == 0) {
            int jc = jfin;
            while (jc != m) {
                int jp = (int)way_lds[jc];
                p_lds[jc] = (jp == m) ? (short)ri : p_lds[jp];
                jc = jp;
            }
        }
        __syncthreads();
    }

    // ---- write outputs: [per_prop (B*Q), mask (B*Q)] as float ----
#pragma unroll
    for (int k = 0; k < CPT; k++) {
        int j = jbase + k;
        short pj = p_lds[j];
        out[(size_t)b * BQ + j] = (pj >= 0) ? (float)pj : 0.0f;
        out[(size_t)NB * BQ + (size_t)b * BQ + j] = (pj >= 0) ? 1.0f : 0.0f;
    }
}

extern "C" void kernel_launch(void* const* d_in, const int* in_sizes, int n_in,
                              void* d_out, int out_size, void* d_ws, size_t ws_size,
                              hipStream_t stream) {
    const float* sem    = (const float*)d_in[0];  // [B,Q,C]
    const float* objp   = (const float*)d_in[1];  // [B,Q]
    const float* cent   = (const float*)d_in[2];  // [B,Q,G]
    const float* giou   = (const float*)d_in[3];  // [B,Q,G]
    const int*   labels = (const int*)d_in[4];    // [B,G]
    const int*   nact   = (const int*)d_in[5];    // [B]
    float* out  = (float*)d_out;                  // [2*B*Q]
    float* cost = (float*)d_ws;                   // [B][G][Q] = 16 MB

    dim3 bgrid(BQ / TQ, NB);
    build_cost_kernel<<<bgrid, BBS, 0, stream>>>(sem, objp, cent, giou,
                                                 labels, nact, cost);
    matcher_kernel<<<NB, BS, 0, stream>>>(cost, nact, out);
}